// Round 7
// baseline (1651.797 us; speedup 1.0000x reference)
//
#include <hip/hip_runtime.h>

// PatientMeanEncoder: causal nonzero-mean pool over concat(timesteps, MLP(dem)).
// N=64, L=2048, C_IN=256, DEM=10, hidden 40 -> 20, C_OUT = 276.
//
// R5 post-mortem: 3-kernel version ~105 us total, but reads the input twice.
// R6/R7: single-pass decoupled-lookback scan (rocPRIM-style):
//   - one wave per (n, seg) unit, SEG=128 -> LSEG=16 rows held in registers
//   - atomic ticket gives wave-ordered virtual ids (deadlock-free lookback)
//   - publish partial -> lookback over predecessor flags -> publish inclusive
//   - compute + NT-store output rows from the registers (no second read)
//   - cross-XCD visibility: agent-scope atomic flags + agent acquire/release
//     fences (wave-level s_waitcnt + L2 wb/inv cover all 64 lanes' stores)
// R7 fix: __ATOMIC_RELAXED (std constants) for __hip_atomic_* memory order.
//
// dem channels are constant along l, so causal nonzero-mean == the constant
// itself (v>0: (l+1)v/(l+1)=v; v==0: 0/max(0,1)=0); fused into row stores.

#define NB 64
#define LL 2048
#define CIN 256
#define COUT 276
#define DEMD 10
#define H1 40
#define H2 20
#define SEG 128
#define LSEG (LL / SEG)      // 16 rows per unit
#define NUNITS (NB * SEG)    // 8192 waves

typedef float vfloat4 __attribute__((ext_vector_type(4)));

static __device__ __forceinline__ void nt_store4(float* p, float4 v) {
    vfloat4 t = {v.x, v.y, v.z, v.w};
    __builtin_nontemporal_store(t, (vfloat4*)p);
}

__global__ __launch_bounds__(256) void pme_onepass(
    const float* __restrict__ ts,    // (N, L, 256)
    const float* __restrict__ dem,   // (N, 10)
    const float* __restrict__ W1, const float* __restrict__ b1,
    const float* __restrict__ W2, const float* __restrict__ b2,
    float* __restrict__ out,         // (N, L, 276)
    unsigned int* __restrict__ flags,   // NUNITS; 0=none, 1=partial, 2=inclusive
    unsigned int* __restrict__ ticket,  // 1
    float4* __restrict__ pvals,      // NUNITS * 128 (per-lane 2 float4)
    float4* __restrict__ ivals)      // NUNITS * 128
{
    const int lane = threadIdx.x & 63;

    // ---- wave-ordered ticket: virtual id matches execution start order ----
    unsigned int t0 = 0;
    if (lane == 0) t0 = atomicAdd(ticket, 1u);
    const unsigned int vid = __builtin_amdgcn_readfirstlane(t0);
    const int n   = vid >> 7;            // vid / SEG
    const int seg = vid & (SEG - 1);
    const unsigned int base = vid - seg; // n * SEG

    // ---- load the whole segment into registers (the single HBM read) ----
    const float4* tp = (const float4*)(ts + ((size_t)n * LL + seg * LSEG) * CIN) + lane;
    float4 v[LSEG];
#pragma unroll
    for (int u = 0; u < LSEG; ++u)
        v[u] = tp[(size_t)u * (CIN / 4)];

    // ---- dem MLP (wave-uniform; overlaps the data-load latency) ----
    const float* dn = dem + n * DEMD;
    float4 e4q;
    {
        float h[H1];
#pragma unroll
        for (int k = 0; k < H1; ++k) {
            float hk = b1[k];
#pragma unroll
            for (int i = 0; i < DEMD; ++i)
                hk += dn[i] * W1[i * H1 + k];
            h[k] = fmaxf(hk, 0.f);
        }
        const int q = (lane < 5) ? lane : 0;
        float e0 = b2[q * 4 + 0], e1 = b2[q * 4 + 1], e2 = b2[q * 4 + 2], e3 = b2[q * 4 + 3];
#pragma unroll
        for (int k = 0; k < H1; ++k) {
            e0 += h[k] * W2[k * H2 + q * 4 + 0];
            e1 += h[k] * W2[k * H2 + q * 4 + 1];
            e2 += h[k] * W2[k * H2 + q * 4 + 2];
            e3 += h[k] * W2[k * H2 + q * 4 + 3];
        }
        e4q = make_float4(fmaxf(e0, 0.f), fmaxf(e1, 0.f), fmaxf(e2, 0.f), fmaxf(e3, 0.f));
    }

    // ---- local (sum, count) over the segment ----
    float4 sum = make_float4(0.f, 0.f, 0.f, 0.f);
    float4 cnt = make_float4(0.f, 0.f, 0.f, 0.f);
#pragma unroll
    for (int u = 0; u < LSEG; ++u) {
        float4 x = v[u];
        sum.x += x.x; cnt.x += (x.x != 0.f) ? 1.f : 0.f;
        sum.y += x.y; cnt.y += (x.y != 0.f) ? 1.f : 0.f;
        sum.z += x.z; cnt.z += (x.z != 0.f) ? 1.f : 0.f;
        sum.w += x.w; cnt.w += (x.w != 0.f) ? 1.f : 0.f;
    }

    // ---- publish partial (unblocks successors before we look back) ----
    if (seg > 0) {
        float4* pv = pvals + (size_t)vid * 128 + lane * 2;
        pv[0] = make_float4(sum.x, cnt.x, sum.y, cnt.y);
        pv[1] = make_float4(sum.z, cnt.z, sum.w, cnt.w);
        __builtin_amdgcn_fence(__ATOMIC_RELEASE, "agent");
        if (lane == 0)
            __hip_atomic_store(&flags[vid], 1u, __ATOMIC_RELAXED,
                               __HIP_MEMORY_SCOPE_AGENT);
    }

    // ---- decoupled lookback: accumulate exclusive prefix ----
    float4 eacc = make_float4(0.f, 0.f, 0.f, 0.f);
    float4 ecnt = make_float4(0.f, 0.f, 0.f, 0.f);
    if (seg > 0) {
        int s = seg - 1;
        for (;;) {
            unsigned int f;
            do {
                f = __hip_atomic_load(&flags[base + s], __ATOMIC_RELAXED,
                                      __HIP_MEMORY_SCOPE_AGENT);
                if (f == 0) __builtin_amdgcn_s_sleep(1);
            } while (f == 0);
            __builtin_amdgcn_fence(__ATOMIC_ACQUIRE, "agent");
            const float4* src = ((f == 2u) ? ivals : pvals) + (size_t)(base + s) * 128 + lane * 2;
            float4 a = src[0], b = src[1];
            eacc.x += a.x; ecnt.x += a.y;
            eacc.y += a.z; ecnt.y += a.w;
            eacc.z += b.x; ecnt.z += b.y;
            eacc.w += b.z; ecnt.w += b.w;
            if (f == 2u) break;
            --s;
        }
    }

    // ---- publish inclusive prefix (skip for the last segment of a chain) ----
    if (seg < SEG - 1) {
        float4* iv = ivals + (size_t)vid * 128 + lane * 2;
        iv[0] = make_float4(eacc.x + sum.x, ecnt.x + cnt.x, eacc.y + sum.y, ecnt.y + cnt.y);
        iv[1] = make_float4(eacc.z + sum.z, ecnt.z + cnt.z, eacc.w + sum.w, ecnt.w + cnt.w);
        __builtin_amdgcn_fence(__ATOMIC_RELEASE, "agent");
        if (lane == 0)
            __hip_atomic_store(&flags[vid], 2u, __ATOMIC_RELAXED,
                               __HIP_MEMORY_SCOPE_AGENT);
    }

    // ---- scan + store output rows from registers (no second read) ----
    float* oprow = out + ((size_t)n * LL + seg * LSEG) * COUT;
    float4 acc = eacc, ct = ecnt;
#pragma unroll
    for (int u = 0; u < LSEG; ++u) {
        float4 x = v[u];
        float4 r;
        acc.x += x.x; ct.x += (x.x != 0.f) ? 1.f : 0.f;
        acc.y += x.y; ct.y += (x.y != 0.f) ? 1.f : 0.f;
        acc.z += x.z; ct.z += (x.z != 0.f) ? 1.f : 0.f;
        acc.w += x.w; ct.w += (x.w != 0.f) ? 1.f : 0.f;
        r.x = fmaxf(acc.x * __builtin_amdgcn_rcpf(fmaxf(ct.x, 1.f)), 0.f);
        r.y = fmaxf(acc.y * __builtin_amdgcn_rcpf(fmaxf(ct.y, 1.f)), 0.f);
        r.z = fmaxf(acc.z * __builtin_amdgcn_rcpf(fmaxf(ct.z, 1.f)), 0.f);
        r.w = fmaxf(acc.w * __builtin_amdgcn_rcpf(fmaxf(ct.w, 1.f)), 0.f);
        float* rowp = oprow + (size_t)u * COUT;
        nt_store4(rowp + lane * 4, r);             // channels 0..255, coalesced
        if (lane < 5)
            nt_store4(rowp + CIN + lane * 4, e4q); // channels 256..275
    }
}

extern "C" void kernel_launch(void* const* d_in, const int* in_sizes, int n_in,
                              void* d_out, int out_size, void* d_ws, size_t ws_size,
                              hipStream_t stream) {
    const float* ts  = (const float*)d_in[0];
    const float* dem = (const float*)d_in[1];
    const float* W1  = (const float*)d_in[2];
    const float* b1  = (const float*)d_in[3];
    const float* W2  = (const float*)d_in[4];
    const float* b2  = (const float*)d_in[5];
    float* out = (float*)d_out;

    // ws layout: [flags: NUNITS u32][ticket: u32] ... pad to 64 KB ...
    //            [pvals: NUNITS*2KB = 16 MB][ivals: 16 MB]
    unsigned int* flags  = (unsigned int*)d_ws;
    unsigned int* ticket = flags + NUNITS;
    float4* pvals = (float4*)((char*)d_ws + 65536);
    float4* ivals = pvals + (size_t)NUNITS * 128;

    // zero flags + ticket (ws is poisoned 0xAA before every timed launch)
    (void)hipMemsetAsync(d_ws, 0, 65536, stream);

    pme_onepass<<<NUNITS / 4, 256, 0, stream>>>(ts, dem, W1, b1, W2, b2, out,
                                                flags, ticket, pvals, ivals);
}